// Round 4
// baseline (583.021 us; speedup 1.0000x reference)
//
#include <hip/hip_runtime.h>
#include <math.h>

#define TPTS 200000
#define BB 2
#define NPTS (BB*TPTS)
#define GRID3 32768
#define BG 65536   // BB * GRID3
#define SROWS 176  // staged rows per block (64 pts + cell overhang; max cell ~30)

typedef __attribute__((ext_vector_type(8))) __bf16 bf16x8;
typedef __attribute__((ext_vector_type(4))) float f32x4;
typedef unsigned short ushort_t;

#define MFMA16(a,b,c) __builtin_amdgcn_mfma_f32_16x16x32_bf16(a,b,c,0,0,0)

__device__ __forceinline__ void split8(const float* v, bf16x8& hi, bf16x8& lo)
{
#pragma unroll
  for (int j = 0; j < 8; j++) {
    float f = v[j];
    __bf16 h = (__bf16)f;
    hi[j] = h;
    lo[j] = (__bf16)(f - (float)h);   // exact residual, rounded to bf16
  }
}

// cell id: must match reference fp32 arithmetic exactly
__device__ __forceinline__ int cellof(float p0, float p1, float p2, int t)
{
  const float DEN = (float)(1.0 + 0.1 + 1e-3);
  const float HI  = (float)(1.0 - 1e-3);
  float n0 = fminf(fmaxf(p0/DEN + 0.5f, 0.f), HI);
  float n1 = fminf(fmaxf(p1/DEN + 0.5f, 0.f), HI);
  float n2 = fminf(fmaxf(p2/DEN + 0.5f, 0.f), HI);
  int c0 = (int)floorf(n0*32.f), c1 = (int)floorf(n1*32.f), c2 = (int)floorf(n2*32.f);
  return c0 + 32*(c1 + 32*c2) + (t >= TPTS ? GRID3 : 0);
}

__global__ __launch_bounds__(256) void k_hist(
    const float* __restrict__ p, int* __restrict__ gbuf, int* __restrict__ hist)
{
  int t = blockIdx.x*256 + threadIdx.x;
  if (t >= NPTS) return;
  int g = cellof(p[3*t], p[3*t+1], p[3*t+2], t);
  gbuf[t] = g;
  atomicAdd(hist + g, 1);
}

// 3-kernel parallel exclusive scan of hist[BG]
__global__ __launch_bounds__(256) void k_scanA(
    const int* __restrict__ hist, int* __restrict__ texcl, int* __restrict__ bsum)
{
  __shared__ int sm[256];
  int tid = threadIdx.x;
  int t = blockIdx.x*256 + tid;
  int v = hist[t];
  sm[tid] = v; __syncthreads();
  for (int off = 1; off < 256; off <<= 1) {
    int x = sm[tid];
    int u = (tid >= off) ? sm[tid-off] : 0;
    __syncthreads();
    sm[tid] = x + u;
    __syncthreads();
  }
  texcl[t] = sm[tid] - v;
  if (tid == 255) bsum[blockIdx.x] = sm[255];
}

__global__ __launch_bounds__(256) void k_scanB(
    const int* __restrict__ bsum, int* __restrict__ boff)
{
  __shared__ int sm[256];
  int tid = threadIdx.x;
  int v = bsum[tid];
  sm[tid] = v; __syncthreads();
  for (int off = 1; off < 256; off <<= 1) {
    int x = sm[tid];
    int u = (tid >= off) ? sm[tid-off] : 0;
    __syncthreads();
    sm[tid] = x + u;
    __syncthreads();
  }
  boff[tid] = sm[tid] - v;   // exclusive block offsets
}

__global__ __launch_bounds__(256) void k_scanC(
    const int* __restrict__ texcl, const int* __restrict__ boff,
    int* __restrict__ start, int* __restrict__ cursor)
{
  int t = blockIdx.x*256 + threadIdx.x;
  int v = boff[blockIdx.x] + texcl[t];
  start[t] = v; cursor[t] = v;
  if (t == 0) start[BG] = NPTS;
}

__global__ __launch_bounds__(256) void k_scatter(
    const float* __restrict__ p, const int* __restrict__ gbuf,
    int* __restrict__ cursor, float* __restrict__ p_sorted, int* __restrict__ gsort)
{
  int t = blockIdx.x*256 + threadIdx.x;
  if (t >= NPTS) return;
  int g = gbuf[t];
  int slot = atomicAdd(cursor + g, 1);
  gsort[slot] = g;
  p_sorted[3*slot]   = p[3*t];
  p_sorted[3*slot+1] = p[3*t+1];
  p_sorted[3*slot+2] = p[3*t+2];
}

// pack weights into MFMA B-fragment order (bf16 hi/lo), once.
// frags 0..99: resblock stages; 100..103: wc; 104..119: Wp (60x64, zero-padded K)
__global__ void k_pack(
    const float* __restrict__ f0w, const float* __restrict__ scw,
    const float* __restrict__ f1w, const float* __restrict__ wc,
    const float* __restrict__ Wp,
    ushort_t* __restrict__ wpack)
{
  int f = blockIdx.x, l = threadIdx.x;
  if (f >= 104) {
    int idx = f - 104;
    int c = idx >> 3, t = (idx >> 1) & 3, e = idx & 1;
#pragma unroll
    for (int j = 0; j < 8; j++) {
      int k = c*32 + (l>>4)*8 + j, n = t*16 + (l&15);
      float v = (k < 60) ? Wp[k*64 + n] : 0.f;
      __bf16 h = (__bf16)v;
      __bf16 out = (e == 0) ? h : (__bf16)(v - (float)h);
      union { __bf16 b; ushort_t u; } cv; cv.b = out;
      wpack[((size_t)f*64 + l)*8 + j] = cv.u;
    }
    return;
  }
  const float* W; int c, t, e;
  if (f < 100) {
    int s = f / 20, r = f % 20;
    if (r < 8)       { W = f0w + s*2048; c = r>>2;        t = (r>>1)&1; e = r&1; }
    else if (r < 16) { int q = r-8;  W = scw + s*2048; c = q>>2; t = (q>>1)&1; e = q&1; }
    else             { int q = r-16; W = f1w + s*1024; c = 0;    t = q>>1;     e = q&1; }
  } else { int q = f-100; W = wc; c = 0; t = q>>1; e = q&1; }
#pragma unroll
  for (int j = 0; j < 8; j++) {
    int k = c*32 + (l>>4)*8 + j, n = t*16 + (l&15);
    float v = W[k*32 + n];
    __bf16 h = (__bf16)v;
    __bf16 out = (e == 0) ? h : (__bf16)(v - (float)h);
    union { __bf16 b; ushort_t u; } cv; cv.b = out;
    wpack[((size_t)f*64 + l)*8 + j] = cv.u;
  }
}

// shared resblock body for one 16-row tile: xv (own row + pooled) -> yacc.
// hb is a wave-private 576-float LDS scratch region (h transpose).
__device__ __forceinline__ void resblock16(
    const float xv[2][8],
    const ushort_t* __restrict__ wp,
    const float* __restrict__ b0, const float* __restrict__ b1,
    int m, int q, int lane, float* hb, f32x4 yacc[2])
{
  bf16x8 w0f[2][2][2], wsf[2][2][2], w1f[2][2];
#pragma unroll
  for (int c = 0; c < 2; c++)
#pragma unroll
    for (int t = 0; t < 2; t++)
#pragma unroll
      for (int e2 = 0; e2 < 2; e2++) {
        w0f[c][t][e2] = *(const bf16x8*)(wp + ((size_t)(((c*2+t)*2+e2)    )*64 + lane)*8);
        wsf[c][t][e2] = *(const bf16x8*)(wp + ((size_t)(((c*2+t)*2+e2) + 8)*64 + lane)*8);
      }
#pragma unroll
  for (int t = 0; t < 2; t++)
#pragma unroll
    for (int e2 = 0; e2 < 2; e2++)
      w1f[t][e2] = *(const bf16x8*)(wp + ((size_t)(16 + t*2 + e2)*64 + lane)*8);

  bf16x8 axh[2], axl[2], arh[2], arl[2];
#pragma unroll
  for (int c = 0; c < 2; c++) {
    float r[8];
#pragma unroll
    for (int j = 0; j < 8; j++) r[j] = fmaxf(xv[c][j], 0.f);
    split8(xv[c], axh[c], axl[c]);
    split8(r,     arh[c], arl[c]);
  }

  f32x4 hacc[2];
#pragma unroll
  for (int t = 0; t < 2; t++) {
    float bb0 = b0[m + 16*t], bb1 = b1[m + 16*t];
    hacc[t] = (f32x4){bb0,bb0,bb0,bb0};
    yacc[t] = (f32x4){bb1,bb1,bb1,bb1};
  }

#pragma unroll
  for (int c = 0; c < 2; c++)
#pragma unroll
    for (int t = 0; t < 2; t++) {
      hacc[t] = MFMA16(arh[c], w0f[c][t][0], hacc[t]);
      hacc[t] = MFMA16(arl[c], w0f[c][t][0], hacc[t]);
      hacc[t] = MFMA16(arh[c], w0f[c][t][1], hacc[t]);
      yacc[t] = MFMA16(axh[c], wsf[c][t][0], yacc[t]);
      yacc[t] = MFMA16(axl[c], wsf[c][t][0], yacc[t]);
      yacc[t] = MFMA16(axh[c], wsf[c][t][1], yacc[t]);
    }

  // h -> A-layout via wave-private LDS (no block barrier needed)
#pragma unroll
  for (int t = 0; t < 2; t++)
#pragma unroll
    for (int r2 = 0; r2 < 4; r2++)
      hb[(q*4+r2)*36 + m + 16*t] = fmaxf(hacc[t][r2], 0.f);
  __threadfence_block();
  float hv[8];
#pragma unroll
  for (int j = 0; j < 8; j++) hv[j] = hb[m*36 + q*8 + j];
  bf16x8 hh, hl; split8(hv, hh, hl);
#pragma unroll
  for (int t = 0; t < 2; t++) {
    yacc[t] = MFMA16(hh, w1f[t][0], yacc[t]);
    yacc[t] = MFMA16(hl, w1f[t][0], yacc[t]);
    yacc[t] = MFMA16(hh, w1f[t][1], yacc[t]);
  }
}

// MEGA: whole network in one kernel. Block owns 64 sorted points; stages its
// full cell range [s,e) (<=SROWS rows, cells complete) and runs all 5
// resblocks + fc_c + per-cell mean entirely in LDS. No inter-stage global
// traffic.
__global__ __launch_bounds__(256, 3) void k_mega(
    const float* __restrict__ ps,
    const int* __restrict__ gsort, const int* __restrict__ start,
    const ushort_t* __restrict__ wpack,
    const float* __restrict__ bp,
    const float* __restrict__ f0b, const float* __restrict__ f1b,
    const float* __restrict__ bc,
    float* __restrict__ outp)
{
  __shared__ float cur[SROWS*36];   // activations, row-major [row][36]
  __shared__ float scr[4608];       // PE: per-wave 16x68 transpose; later: cmax[64*36] + hbuf[4*576]
  __shared__ int rowslot[SROWS];    // row -> cell-start row
  __shared__ int cid[SROWS];        // cell-start row -> compact cell id
  __shared__ int clist[64];         // compact cell id -> cell-start row
  __shared__ int ccnt;

  int tid = threadIdx.x;
  int wave = tid >> 6, lane = tid & 63;
  int m = lane & 15, q = lane >> 4;
  int P0 = blockIdx.x*64;
  int s = start[gsort[P0]];
  int e = start[gsort[P0+63] + 1];
  int n = e - s; if (n > SROWS) n = SROWS;
  int T = (n + 15) >> 4;

  if (tid == 0) ccnt = 0;
  for (int r = tid; r < SROWS; r += 256) rowslot[r] = 0;
  __syncthreads();
  for (int r = tid; r < n; r += 256) {
    int cs = start[gsort[s + r]] - s;
    rowslot[r] = cs;
    if (cs == r) { int id = atomicAdd(&ccnt, 1); clist[id] = r; cid[r] = id; }
  }
  __syncthreads();
  int nc = ccnt;

  // ---- stage 0: PE -> fc_pos -> resblock0, for ALL staged rows ----
  {
    const ushort_t* wpPE = wpack + (size_t)104*512;
    const ushort_t* wp0  = wpack;
    const float* b00 = f0b, *b10 = f1b;
    float* xl = scr + wave*1152;   // wave-private 16x68 (also reused as hb)
    const float PIF = 3.14159265358979323846f;
    for (int t = wave; t < T; t += 4) {
      int rbase = t*16;
      int rr = rbase + m;
      int rsrc = (rr < n) ? rr : (n - 1);
      const float* pp = ps + 3*(size_t)(s + rsrc);
      float p0 = pp[0], p1 = pp[1], p2 = pp[2];
      float u0 = 2.f*p0 - 1.f, u1 = 2.f*p1 - 1.f, u2 = 2.f*p2 - 1.f;

      float pe[2][8];
#pragma unroll
      for (int c2 = 0; c2 < 2; c2++) {
#pragma unroll
        for (int jj = 0; jj < 8; jj++) {
          int pei = c2*32 + q*8 + jj;
          int l = (pei * 43691) >> 18;       // pei / 6
          int r6 = pei - l*6;
          bool issin = (r6 < 3);
          int d = issin ? r6 : (r6 - 3);
          float ud = (d == 0) ? u0 : ((d == 1) ? u1 : u2);
          float xval = ldexpf(ud, l);
          float red = xval - 2.f*rintf(0.5f*xval);
          float ang = PIF*red + (issin ? 0.f : 1.5707963267948966f);
          float v = __sinf(ang);
          pe[c2][jj] = (pei < 60) ? v : 0.f;
        }
      }
      bf16x8 peh[2], pel[2];
      split8(pe[0], peh[0], pel[0]);
      split8(pe[1], peh[1], pel[1]);

      f32x4 xacc[4];
#pragma unroll
      for (int tt = 0; tt < 4; tt++) {
        float bb = bp[tt*16 + m];
        xacc[tt] = (f32x4){bb,bb,bb,bb};
      }
#pragma unroll
      for (int c2 = 0; c2 < 2; c2++)
#pragma unroll
        for (int tt = 0; tt < 4; tt++) {
          bf16x8 bh = *(const bf16x8*)(wpPE + ((size_t)((c2*4+tt)*2    )*64 + lane)*8);
          bf16x8 bl = *(const bf16x8*)(wpPE + ((size_t)((c2*4+tt)*2 + 1)*64 + lane)*8);
          xacc[tt] = MFMA16(peh[c2], bh, xacc[tt]);
          xacc[tt] = MFMA16(pel[c2], bh, xacc[tt]);
          xacc[tt] = MFMA16(peh[c2], bl, xacc[tt]);
        }

      // D-layout -> A-layout via wave-private LDS
#pragma unroll
      for (int tt = 0; tt < 4; tt++)
#pragma unroll
        for (int r2 = 0; r2 < 4; r2++)
          xl[(q*4+r2)*68 + tt*16 + m] = xacc[tt][r2];
      __threadfence_block();
      float xv[2][8];
#pragma unroll
      for (int c2 = 0; c2 < 2; c2++)
#pragma unroll
        for (int jj = 0; jj < 8; jj++)
          xv[c2][jj] = xl[m*68 + c2*32 + q*8 + jj];
      __threadfence_block();   // xl reads done before reuse as hb

      f32x4 yacc[2];
      resblock16(xv, wp0, b00, b10, m, q, lane, xl, yacc);

#pragma unroll
      for (int tt = 0; tt < 2; tt++)
#pragma unroll
        for (int r2 = 0; r2 < 4; r2++)
          cur[(rbase + q*4 + r2)*36 + m + 16*tt] = yacc[tt][r2];
    }
  }
  __syncthreads();

  // ---- stages 1..4: pool (per-cell max) + resblock, all in LDS ----
  float* cmax = scr;                    // [64][36]
  float* hbw  = scr + 2304 + wave*576;  // wave-private h scratch
  for (int st = 1; st <= 4; st++) {
    const ushort_t* wp = wpack + (size_t)st*20*512;
    const float* b0 = f0b + st*32;
    const float* b1 = f1b + st*32;

    // cooperative per-cell max (each cell row read once per channel-half)
    for (int it = tid; it < nc*4; it += 256) {
      int ci = it >> 2, qq = it & 3;
      int r0 = clist[ci];
      int re = start[gsort[s + r0] + 1] - s; if (re > n) re = n;
      f32x4 ma = (f32x4){-INFINITY,-INFINITY,-INFINITY,-INFINITY};
      f32x4 mb = ma;
      for (int k = r0; k < re; k++) {
        const float* rr2 = cur + k*36 + qq*8;
        f32x4 va = *(const f32x4*)rr2;
        f32x4 vb = *(const f32x4*)(rr2 + 4);
        ma.x = fmaxf(ma.x, va.x); ma.y = fmaxf(ma.y, va.y);
        ma.z = fmaxf(ma.z, va.z); ma.w = fmaxf(ma.w, va.w);
        mb.x = fmaxf(mb.x, vb.x); mb.y = fmaxf(mb.y, vb.y);
        mb.z = fmaxf(mb.z, vb.z); mb.w = fmaxf(mb.w, vb.w);
      }
      *(f32x4*)(cmax + ci*36 + qq*8)     = ma;
      *(f32x4*)(cmax + ci*36 + qq*8 + 4) = mb;
    }
    __syncthreads();

    // resblock for all tiles, in-place on cur
    for (int t = wave; t < T; t += 4) {
      int rbase = t*16;
      int rr = rbase + m;
      float xv[2][8];
      {
        const float* xr = cur + rr*36 + q*8;
        *(f32x4*)&xv[0][0] = *(const f32x4*)xr;
        *(f32x4*)&xv[0][4] = *(const f32x4*)(xr + 4);
        int cix = cid[rowslot[rr]];
        const float* mr = cmax + cix*36 + q*8;
        *(f32x4*)&xv[1][0] = *(const f32x4*)mr;
        *(f32x4*)&xv[1][4] = *(const f32x4*)(mr + 4);
      }
      f32x4 yacc[2];
      resblock16(xv, wp, b0, b1, m, q, lane, hbw, yacc);
#pragma unroll
      for (int tt = 0; tt < 2; tt++)
#pragma unroll
        for (int r2 = 0; r2 < 4; r2++)
          cur[(rbase + q*4 + r2)*36 + m + 16*tt] = yacc[tt][r2];
    }
    __syncthreads();
  }

  // ---- fc_c for all rows, in-place ----
  {
    const ushort_t* wpc = wpack + (size_t)100*512;
    bf16x8 wcf[2][2];
#pragma unroll
    for (int tt = 0; tt < 2; tt++)
#pragma unroll
      for (int e2 = 0; e2 < 2; e2++)
        wcf[tt][e2] = *(const bf16x8*)(wpc + ((size_t)(tt*2 + e2)*64 + lane)*8);
    for (int t = wave; t < T; t += 4) {
      int rbase = t*16;
      int rr = rbase + m;
      float yv[8];
      const float* yr = cur + rr*36 + q*8;
      *(f32x4*)&yv[0] = *(const f32x4*)yr;
      *(f32x4*)&yv[4] = *(const f32x4*)(yr + 4);
      bf16x8 yh, yl; split8(yv, yh, yl);
      f32x4 cacc[2];
#pragma unroll
      for (int tt = 0; tt < 2; tt++) {
        float bb = bc[m + 16*tt];
        cacc[tt] = (f32x4){bb,bb,bb,bb};
        cacc[tt] = MFMA16(yh, wcf[tt][0], cacc[tt]);
        cacc[tt] = MFMA16(yl, wcf[tt][0], cacc[tt]);
        cacc[tt] = MFMA16(yh, wcf[tt][1], cacc[tt]);
      }
#pragma unroll
      for (int tt = 0; tt < 2; tt++)
#pragma unroll
        for (int r2 = 0; r2 < 4; r2++)
          cur[(rbase + q*4 + r2)*36 + m + 16*tt] = cacc[tt][r2];
    }
  }
  __syncthreads();

  // ---- per-cell mean, written by owner block (cell start in our 64 pts) ----
  int rlo = P0 - s;
  for (int it = tid; it < nc*4; it += 256) {
    int ci = it >> 2, qq = it & 3;
    int r0 = clist[ci];
    if (r0 < rlo || r0 >= rlo + 64) continue;   // not our cell
    int g = gsort[s + r0];
    int re = start[g + 1] - s; if (re > n) re = n;
    f32x4 sa = (f32x4){0.f,0.f,0.f,0.f};
    f32x4 sb = sa;
    for (int k = r0; k < re; k++) {
      const float* rr2 = cur + k*36 + qq*8;
      f32x4 va = *(const f32x4*)rr2;
      f32x4 vb = *(const f32x4*)(rr2 + 4);
      sa.x += va.x; sa.y += va.y; sa.z += va.z; sa.w += va.w;
      sb.x += vb.x; sb.y += vb.y; sb.z += vb.z; sb.w += vb.w;
    }
    float inv = 1.f / (float)(re - r0);
    int b = g >> 15, cell = g & 32767;
    size_t ob = ((size_t)b << 20) + cell;
#pragma unroll
    for (int jj = 0; jj < 4; jj++) {
      outp[ob + ((size_t)(qq*8 + jj)     << 15)] = ((const float*)&sa)[jj] * inv;
      outp[ob + ((size_t)(qq*8 + jj + 4) << 15)] = ((const float*)&sb)[jj] * inv;
    }
  }
}

extern "C" void kernel_launch(void* const* d_in, const int* in_sizes, int n_in,
                              void* d_out, int out_size, void* d_ws, size_t ws_size,
                              hipStream_t stream)
{
  const float* p   = (const float*)d_in[0];
  const float* Wp  = (const float*)d_in[1];
  const float* bp  = (const float*)d_in[2];
  const float* f0w = (const float*)d_in[3];
  const float* f0b = (const float*)d_in[4];
  const float* f1w = (const float*)d_in[5];
  const float* f1b = (const float*)d_in[6];
  const float* scw = (const float*)d_in[7];
  const float* wc  = (const float*)d_in[8];
  const float* bc  = (const float*)d_in[9];
  float* outp = (float*)d_out;

  char* wsb = (char*)d_ws;
  int*      gbuf     = (int*)wsb;                         // NPTS
  int*      gsort    = gbuf + NPTS;                       // NPTS
  int*      hist     = gsort + NPTS;                      // BG
  int*      start    = hist + BG;                         // BG+1
  int*      cursor   = start + BG + 1;                    // BG
  int*      texcl    = cursor + BG;                       // BG
  int*      bsum     = texcl + BG;                        // 256
  int*      boff     = bsum + 256;                        // 256
  ushort_t* wpack    = (ushort_t*)(boff + 256);           // 120*512 ushort
  float*    p_sorted = (float*)(wpack + (size_t)120*512); // NPTS*3

  dim3 blk(256);
  dim3 gpts((NPTS + 255)/256);
  dim3 gmega(NPTS/64);          // 6250 blocks
  dim3 gscan(BG/256);           // 256 blocks

  hipMemsetAsync(hist, 0, (size_t)BG*4, stream);
  hipMemsetAsync(outp, 0, (size_t)BG*32*4, stream);
  hipLaunchKernelGGL(k_hist, gpts, blk, 0, stream, p, gbuf, hist);
  hipLaunchKernelGGL(k_scanA, gscan, blk, 0, stream, hist, texcl, bsum);
  hipLaunchKernelGGL(k_scanB, dim3(1), blk, 0, stream, bsum, boff);
  hipLaunchKernelGGL(k_scanC, gscan, blk, 0, stream, texcl, boff, start, cursor);
  hipLaunchKernelGGL(k_scatter, gpts, blk, 0, stream, p, gbuf, cursor, p_sorted, gsort);
  hipLaunchKernelGGL(k_pack, dim3(120), dim3(64), 0, stream, f0w, scw, f1w, wc, Wp, wpack);
  hipLaunchKernelGGL(k_mega, gmega, blk, 0, stream,
                     p_sorted, gsort, start, wpack, bp, f0b, f1b, bc, outp);
}

// Round 5
// 557.705 us; speedup vs baseline: 1.0454x; 1.0454x over previous
//
#include <hip/hip_runtime.h>
#include <math.h>

#define TPTS 200000
#define BB 2
#define NPTS (BB*TPTS)
#define GRID3 32768
#define BG 65536   // BB * GRID3
#define SROWS 176  // staged rows per block (64 pts + cell overhang; max cell ~30)

typedef __attribute__((ext_vector_type(8))) __bf16 bf16x8;
typedef __attribute__((ext_vector_type(4))) float f32x4;
typedef unsigned short ushort_t;

#define MFMA16(a,b,c) __builtin_amdgcn_mfma_f32_16x16x32_bf16(a,b,c,0,0,0)

__device__ __forceinline__ f32x4 relu4(f32x4 v)
{
  return (f32x4){fmaxf(v.x,0.f), fmaxf(v.y,0.f), fmaxf(v.z,0.f), fmaxf(v.w,0.f)};
}

// split 4 floats (vector reg) into bf16 hi + exact-residual lo, lanes [base,base+4)
__device__ __forceinline__ void split4(f32x4 v, bf16x8& hi, bf16x8& lo, int base)
{
#pragma unroll
  for (int j = 0; j < 4; j++) {
    float f = v[j];
    __bf16 h = (__bf16)f;
    hi[base+j] = h;
    lo[base+j] = (__bf16)(f - (float)h);
  }
}

// cell id: must match reference fp32 arithmetic exactly
__device__ __forceinline__ int cellof(float p0, float p1, float p2, int t)
{
  const float DEN = (float)(1.0 + 0.1 + 1e-3);
  const float HI  = (float)(1.0 - 1e-3);
  float n0 = fminf(fmaxf(p0/DEN + 0.5f, 0.f), HI);
  float n1 = fminf(fmaxf(p1/DEN + 0.5f, 0.f), HI);
  float n2 = fminf(fmaxf(p2/DEN + 0.5f, 0.f), HI);
  int c0 = (int)floorf(n0*32.f), c1 = (int)floorf(n1*32.f), c2 = (int)floorf(n2*32.f);
  return c0 + 32*(c1 + 32*c2) + (t >= TPTS ? GRID3 : 0);
}

__global__ __launch_bounds__(256) void k_hist(
    const float* __restrict__ p, int* __restrict__ gbuf, int* __restrict__ hist)
{
  int t = blockIdx.x*256 + threadIdx.x;
  if (t >= NPTS) return;
  int g = cellof(p[3*t], p[3*t+1], p[3*t+2], t);
  gbuf[t] = g;
  atomicAdd(hist + g, 1);
}

// 3-kernel parallel exclusive scan of hist[BG]
__global__ __launch_bounds__(256) void k_scanA(
    const int* __restrict__ hist, int* __restrict__ texcl, int* __restrict__ bsum)
{
  __shared__ int sm[256];
  int tid = threadIdx.x;
  int t = blockIdx.x*256 + tid;
  int v = hist[t];
  sm[tid] = v; __syncthreads();
  for (int off = 1; off < 256; off <<= 1) {
    int x = sm[tid];
    int u = (tid >= off) ? sm[tid-off] : 0;
    __syncthreads();
    sm[tid] = x + u;
    __syncthreads();
  }
  texcl[t] = sm[tid] - v;
  if (tid == 255) bsum[blockIdx.x] = sm[255];
}

__global__ __launch_bounds__(256) void k_scanB(
    const int* __restrict__ bsum, int* __restrict__ boff)
{
  __shared__ int sm[256];
  int tid = threadIdx.x;
  int v = bsum[tid];
  sm[tid] = v; __syncthreads();
  for (int off = 1; off < 256; off <<= 1) {
    int x = sm[tid];
    int u = (tid >= off) ? sm[tid-off] : 0;
    __syncthreads();
    sm[tid] = x + u;
    __syncthreads();
  }
  boff[tid] = sm[tid] - v;   // exclusive block offsets
}

__global__ __launch_bounds__(256) void k_scanC(
    const int* __restrict__ texcl, const int* __restrict__ boff,
    int* __restrict__ start, int* __restrict__ cursor)
{
  int t = blockIdx.x*256 + threadIdx.x;
  int v = boff[blockIdx.x] + texcl[t];
  start[t] = v; cursor[t] = v;
  if (t == 0) start[BG] = NPTS;
}

__global__ __launch_bounds__(256) void k_scatter(
    const float* __restrict__ p, const int* __restrict__ gbuf,
    int* __restrict__ cursor, float* __restrict__ p_sorted, int* __restrict__ gsort)
{
  int t = blockIdx.x*256 + threadIdx.x;
  if (t >= NPTS) return;
  int g = gbuf[t];
  int slot = atomicAdd(cursor + g, 1);
  gsort[slot] = g;
  p_sorted[3*slot]   = p[3*t];
  p_sorted[3*slot+1] = p[3*t+1];
  p_sorted[3*slot+2] = p[3*t+2];
}

// pack weights into MFMA B-fragment order (bf16 hi/lo), once.
// frags 0..99: resblock stages; 100..103: wc; 104..119: Wp (60x64, zero-padded K)
__global__ void k_pack(
    const float* __restrict__ f0w, const float* __restrict__ scw,
    const float* __restrict__ f1w, const float* __restrict__ wc,
    const float* __restrict__ Wp,
    ushort_t* __restrict__ wpack)
{
  int f = blockIdx.x, l = threadIdx.x;
  if (f >= 104) {
    int idx = f - 104;
    int c = idx >> 3, t = (idx >> 1) & 3, e = idx & 1;
#pragma unroll
    for (int j = 0; j < 8; j++) {
      int k = c*32 + (l>>4)*8 + j, n = t*16 + (l&15);
      float v = (k < 60) ? Wp[k*64 + n] : 0.f;
      __bf16 h = (__bf16)v;
      __bf16 out = (e == 0) ? h : (__bf16)(v - (float)h);
      union { __bf16 b; ushort_t u; } cv; cv.b = out;
      wpack[((size_t)f*64 + l)*8 + j] = cv.u;
    }
    return;
  }
  const float* W; int c, t, e;
  if (f < 100) {
    int s = f / 20, r = f % 20;
    if (r < 8)       { W = f0w + s*2048; c = r>>2;        t = (r>>1)&1; e = r&1; }
    else if (r < 16) { int q = r-8;  W = scw + s*2048; c = q>>2; t = (q>>1)&1; e = q&1; }
    else             { int q = r-16; W = f1w + s*1024; c = 0;    t = q>>1;     e = q&1; }
  } else { int q = f-100; W = wc; c = 0; t = q>>1; e = q&1; }
#pragma unroll
  for (int j = 0; j < 8; j++) {
    int k = c*32 + (l>>4)*8 + j, n = t*16 + (l&15);
    float v = W[k*32 + n];
    __bf16 h = (__bf16)v;
    __bf16 out = (e == 0) ? h : (__bf16)(v - (float)h);
    union { __bf16 b; ushort_t u; } cv; cv.b = out;
    wpack[((size_t)f*64 + l)*8 + j] = cv.u;
  }
}

// resblock for one 16-row tile, all-register activations.
// x0*: own row (K-chunk q), x1*: pooled. wp: 20-frag weight block.
// hb: wave-private LDS scratch (>=576 floats). Outputs y0,y1 (N-tiles 0,1).
#define WF(i) (*(const bf16x8*)(wp + (size_t)(i)*512 + (size_t)lane*8))
__device__ __forceinline__ void resblock_core(
    f32x4 x0a, f32x4 x0b, f32x4 x1a, f32x4 x1b,
    const ushort_t* __restrict__ wp,
    float bh0, float bh1, float by0, float by1,
    int m, int q, int lane, float* hb,
    f32x4& y0, f32x4& y1)
{
  bf16x8 axh0, axl0, axh1, axl1, arh0, arl0, arh1, arl1;
  split4(x0a, axh0, axl0, 0); split4(x0b, axh0, axl0, 4);
  split4(x1a, axh1, axl1, 0); split4(x1b, axh1, axl1, 4);
  split4(relu4(x0a), arh0, arl0, 0); split4(relu4(x0b), arh0, arl0, 4);
  split4(relu4(x1a), arh1, arl1, 0); split4(relu4(x1b), arh1, arl1, 4);

  f32x4 h0 = (f32x4){bh0,bh0,bh0,bh0};
  f32x4 h1 = (f32x4){bh1,bh1,bh1,bh1};
  y0 = (f32x4){by0,by0,by0,by0};
  y1 = (f32x4){by1,by1,by1,by1};

  // c=0 (own row)
  h0 = MFMA16(arh0, WF(0), h0);  h0 = MFMA16(arl0, WF(0), h0);  h0 = MFMA16(arh0, WF(1), h0);
  h1 = MFMA16(arh0, WF(2), h1);  h1 = MFMA16(arl0, WF(2), h1);  h1 = MFMA16(arh0, WF(3), h1);
  y0 = MFMA16(axh0, WF(8), y0);  y0 = MFMA16(axl0, WF(8), y0);  y0 = MFMA16(axh0, WF(9), y0);
  y1 = MFMA16(axh0, WF(10), y1); y1 = MFMA16(axl0, WF(10), y1); y1 = MFMA16(axh0, WF(11), y1);
  // c=1 (pooled)
  h0 = MFMA16(arh1, WF(4), h0);  h0 = MFMA16(arl1, WF(4), h0);  h0 = MFMA16(arh1, WF(5), h0);
  h1 = MFMA16(arh1, WF(6), h1);  h1 = MFMA16(arl1, WF(6), h1);  h1 = MFMA16(arh1, WF(7), h1);
  y0 = MFMA16(axh1, WF(12), y0); y0 = MFMA16(axl1, WF(12), y0); y0 = MFMA16(axh1, WF(13), y0);
  y1 = MFMA16(axh1, WF(14), y1); y1 = MFMA16(axl1, WF(14), y1); y1 = MFMA16(axh1, WF(15), y1);

  // h -> A-layout via wave-private LDS
#pragma unroll
  for (int r2 = 0; r2 < 4; r2++) {
    hb[(q*4+r2)*36 + m]      = fmaxf(h0[r2], 0.f);
    hb[(q*4+r2)*36 + m + 16] = fmaxf(h1[r2], 0.f);
  }
  __threadfence_block();
  f32x4 hva = *(const f32x4*)(hb + m*36 + q*8);
  f32x4 hvb = *(const f32x4*)(hb + m*36 + q*8 + 4);
  __threadfence_block();
  bf16x8 hh, hl;
  split4(hva, hh, hl, 0); split4(hvb, hh, hl, 4);
  y0 = MFMA16(hh, WF(16), y0); y0 = MFMA16(hl, WF(16), y0); y0 = MFMA16(hh, WF(17), y0);
  y1 = MFMA16(hh, WF(18), y1); y1 = MFMA16(hl, WF(18), y1); y1 = MFMA16(hh, WF(19), y1);
}

// MEGA: whole network in one kernel; block stages its full cell range [s,e)
// in LDS and runs all 5 resblocks + fc_c + per-cell mean with no inter-stage
// global traffic. All locals are named vector registers (no scratch).
__global__ __launch_bounds__(256, 3) void k_mega(
    const float* __restrict__ ps,
    const int* __restrict__ gsort, const int* __restrict__ start,
    const ushort_t* __restrict__ wpack,
    const float* __restrict__ bp,
    const float* __restrict__ f0b, const float* __restrict__ f1b,
    const float* __restrict__ bc,
    float* __restrict__ outp)
{
  __shared__ float cur[SROWS*36];   // activations, row-major [row][36]
  __shared__ float scr[4608];       // stage0: per-wave 16x68; later: cmax[64*36] + 4x576 hbuf
  __shared__ int rowslot[SROWS];    // row -> cell-start row
  __shared__ int cid[SROWS];        // cell-start row -> compact cell id
  __shared__ int clist[64];         // compact cell id -> cell-start row
  __shared__ int ccnt;

  int tid = threadIdx.x;
  int wave = tid >> 6, lane = tid & 63;
  int m = lane & 15, q = lane >> 4;
  int P0 = blockIdx.x*64;
  int s = start[gsort[P0]];
  int e = start[gsort[P0+63] + 1];
  int n = e - s; if (n > SROWS) n = SROWS;
  int T = (n + 15) >> 4;

  if (tid == 0) ccnt = 0;
  for (int r = tid; r < SROWS; r += 256) rowslot[r] = 0;
  __syncthreads();
  for (int r = tid; r < n; r += 256) {
    int cs = start[gsort[s + r]] - s;
    rowslot[r] = cs;
    if (cs == r) { int id = atomicAdd(&ccnt, 1); clist[id] = r; cid[r] = id; }
  }
  __syncthreads();
  int nc = ccnt;

  // ---- stage 0: PE -> fc_pos -> resblock0, for ALL staged rows ----
  {
    const ushort_t* wpPE = wpack + (size_t)104*512;
    float* xl = scr + wave*1152;   // wave-private 16x68 transpose / hb scratch
    const float PIF = 3.14159265358979323846f;
    for (int t = wave; t < T; t += 4) {
      int rbase = t*16;
      int rr = rbase + m;
      int rsrc = (rr < n) ? rr : (n - 1);
      const float* pp = ps + 3*(size_t)(s + rsrc);
      float p0 = pp[0], p1 = pp[1], p2 = pp[2];
      float u0 = 2.f*p0 - 1.f, u1 = 2.f*p1 - 1.f, u2 = 2.f*p2 - 1.f;

      f32x4 pe0a, pe0b, pe1a, pe1b;
#pragma unroll
      for (int c2 = 0; c2 < 2; c2++) {
#pragma unroll
        for (int jj = 0; jj < 8; jj++) {
          int pei = c2*32 + q*8 + jj;
          int l = (pei * 43691) >> 18;       // pei / 6
          int r6 = pei - l*6;
          bool issin = (r6 < 3);
          int d = issin ? r6 : (r6 - 3);
          float ud = (d == 0) ? u0 : ((d == 1) ? u1 : u2);
          float xval = ldexpf(ud, l);
          float red = xval - 2.f*rintf(0.5f*xval);
          float ang = PIF*red + (issin ? 0.f : 1.5707963267948966f);
          float v = __sinf(ang);
          float vv = (pei < 60) ? v : 0.f;
          if (c2 == 0) { if (jj < 4) pe0a[jj] = vv; else pe0b[jj-4] = vv; }
          else         { if (jj < 4) pe1a[jj] = vv; else pe1b[jj-4] = vv; }
        }
      }
      bf16x8 peh0, pel0, peh1, pel1;
      split4(pe0a, peh0, pel0, 0); split4(pe0b, peh0, pel0, 4);
      split4(pe1a, peh1, pel1, 0); split4(pe1b, peh1, pel1, 4);

      float bb0 = bp[m], bb1 = bp[16+m], bb2 = bp[32+m], bb3 = bp[48+m];
      f32x4 xacc0 = (f32x4){bb0,bb0,bb0,bb0};
      f32x4 xacc1 = (f32x4){bb1,bb1,bb1,bb1};
      f32x4 xacc2 = (f32x4){bb2,bb2,bb2,bb2};
      f32x4 xacc3 = (f32x4){bb3,bb3,bb3,bb3};
#define WPE(i) (*(const bf16x8*)(wpPE + (size_t)(i)*512 + (size_t)lane*8))
      xacc0 = MFMA16(peh0, WPE(0), xacc0);  xacc0 = MFMA16(pel0, WPE(0), xacc0);  xacc0 = MFMA16(peh0, WPE(1), xacc0);
      xacc1 = MFMA16(peh0, WPE(2), xacc1);  xacc1 = MFMA16(pel0, WPE(2), xacc1);  xacc1 = MFMA16(peh0, WPE(3), xacc1);
      xacc2 = MFMA16(peh0, WPE(4), xacc2);  xacc2 = MFMA16(pel0, WPE(4), xacc2);  xacc2 = MFMA16(peh0, WPE(5), xacc2);
      xacc3 = MFMA16(peh0, WPE(6), xacc3);  xacc3 = MFMA16(pel0, WPE(6), xacc3);  xacc3 = MFMA16(peh0, WPE(7), xacc3);
      xacc0 = MFMA16(peh1, WPE(8), xacc0);  xacc0 = MFMA16(pel1, WPE(8), xacc0);  xacc0 = MFMA16(peh1, WPE(9), xacc0);
      xacc1 = MFMA16(peh1, WPE(10), xacc1); xacc1 = MFMA16(pel1, WPE(10), xacc1); xacc1 = MFMA16(peh1, WPE(11), xacc1);
      xacc2 = MFMA16(peh1, WPE(12), xacc2); xacc2 = MFMA16(pel1, WPE(12), xacc2); xacc2 = MFMA16(peh1, WPE(13), xacc2);
      xacc3 = MFMA16(peh1, WPE(14), xacc3); xacc3 = MFMA16(pel1, WPE(14), xacc3); xacc3 = MFMA16(peh1, WPE(15), xacc3);
#undef WPE

      // D-layout -> A-layout via wave-private LDS
#pragma unroll
      for (int r2 = 0; r2 < 4; r2++) {
        xl[(q*4+r2)*68 +      m] = xacc0[r2];
        xl[(q*4+r2)*68 + 16 + m] = xacc1[r2];
        xl[(q*4+r2)*68 + 32 + m] = xacc2[r2];
        xl[(q*4+r2)*68 + 48 + m] = xacc3[r2];
      }
      __threadfence_block();
      f32x4 x0a = *(const f32x4*)(xl + m*68 + q*8);
      f32x4 x0b = *(const f32x4*)(xl + m*68 + q*8 + 4);
      f32x4 x1a = *(const f32x4*)(xl + m*68 + 32 + q*8);
      f32x4 x1b = *(const f32x4*)(xl + m*68 + 32 + q*8 + 4);
      __threadfence_block();   // xl reads done before reuse as hb

      f32x4 y0, y1;
      resblock_core(x0a, x0b, x1a, x1b, wpack,
                    f0b[m], f0b[16+m], f1b[m], f1b[16+m],
                    m, q, lane, xl, y0, y1);

#pragma unroll
      for (int r2 = 0; r2 < 4; r2++) {
        cur[(rbase + q*4 + r2)*36 + m]      = y0[r2];
        cur[(rbase + q*4 + r2)*36 + m + 16] = y1[r2];
      }
    }
  }
  __syncthreads();

  // ---- stages 1..4: pool (per-cell max) + resblock, all in LDS ----
  float* cmax = scr;                    // [64][36]
  float* hbw  = scr + 2304 + wave*576;  // wave-private h scratch
  for (int st = 1; st <= 4; st++) {
    const ushort_t* wp = wpack + (size_t)st*20*512;
    const float* b0 = f0b + st*32;
    const float* b1 = f1b + st*32;

    // cooperative per-cell max (each cell row read once per channel-half)
    for (int it = tid; it < nc*4; it += 256) {
      int ci = it >> 2, qq = it & 3;
      int r0 = clist[ci];
      int re = start[gsort[s + r0] + 1] - s; if (re > n) re = n;
      f32x4 ma = (f32x4){-INFINITY,-INFINITY,-INFINITY,-INFINITY};
      f32x4 mb = ma;
      for (int k = r0; k < re; k++) {
        const float* rr2 = cur + k*36 + qq*8;
        f32x4 va = *(const f32x4*)rr2;
        f32x4 vb = *(const f32x4*)(rr2 + 4);
        ma.x = fmaxf(ma.x, va.x); ma.y = fmaxf(ma.y, va.y);
        ma.z = fmaxf(ma.z, va.z); ma.w = fmaxf(ma.w, va.w);
        mb.x = fmaxf(mb.x, vb.x); mb.y = fmaxf(mb.y, vb.y);
        mb.z = fmaxf(mb.z, vb.z); mb.w = fmaxf(mb.w, vb.w);
      }
      *(f32x4*)(cmax + ci*36 + qq*8)     = ma;
      *(f32x4*)(cmax + ci*36 + qq*8 + 4) = mb;
    }
    __syncthreads();

    // resblock for all tiles, in-place on cur
    for (int t = wave; t < T; t += 4) {
      int rbase = t*16;
      int rr = rbase + m;
      f32x4 x0a = *(const f32x4*)(cur + rr*36 + q*8);
      f32x4 x0b = *(const f32x4*)(cur + rr*36 + q*8 + 4);
      int cix = cid[rowslot[rr]];
      f32x4 x1a = *(const f32x4*)(cmax + cix*36 + q*8);
      f32x4 x1b = *(const f32x4*)(cmax + cix*36 + q*8 + 4);

      f32x4 y0, y1;
      resblock_core(x0a, x0b, x1a, x1b, wp,
                    b0[m], b0[16+m], b1[m], b1[16+m],
                    m, q, lane, hbw, y0, y1);
#pragma unroll
      for (int r2 = 0; r2 < 4; r2++) {
        cur[(rbase + q*4 + r2)*36 + m]      = y0[r2];
        cur[(rbase + q*4 + r2)*36 + m + 16] = y1[r2];
      }
    }
    __syncthreads();
  }

  // ---- fc_c for all rows, in-place ----
  {
    const ushort_t* wp = wpack + (size_t)100*512;
    for (int t = wave; t < T; t += 4) {
      int rbase = t*16;
      int rr = rbase + m;
      f32x4 ya = *(const f32x4*)(cur + rr*36 + q*8);
      f32x4 yb = *(const f32x4*)(cur + rr*36 + q*8 + 4);
      bf16x8 yh, yl;
      split4(ya, yh, yl, 0); split4(yb, yh, yl, 4);
      float bb0 = bc[m], bb1 = bc[16+m];
      f32x4 c0 = (f32x4){bb0,bb0,bb0,bb0};
      f32x4 c1 = (f32x4){bb1,bb1,bb1,bb1};
      c0 = MFMA16(yh, WF(0), c0); c0 = MFMA16(yl, WF(0), c0); c0 = MFMA16(yh, WF(1), c0);
      c1 = MFMA16(yh, WF(2), c1); c1 = MFMA16(yl, WF(2), c1); c1 = MFMA16(yh, WF(3), c1);
      // wait for all waves' reads of this tile's rows? rows are tile-private -> safe
#pragma unroll
      for (int r2 = 0; r2 < 4; r2++) {
        cur[(rbase + q*4 + r2)*36 + m]      = c0[r2];
        cur[(rbase + q*4 + r2)*36 + m + 16] = c1[r2];
      }
    }
  }
  __syncthreads();

  // ---- per-cell mean, written by owner block (cell start in our 64 pts) ----
  int rlo = P0 - s;
  for (int it = tid; it < nc*4; it += 256) {
    int ci = it >> 2, qq = it & 3;
    int r0 = clist[ci];
    if (r0 < rlo || r0 >= rlo + 64) continue;   // not our cell
    int g = gsort[s + r0];
    int re = start[g + 1] - s; if (re > n) re = n;
    f32x4 sa = (f32x4){0.f,0.f,0.f,0.f};
    f32x4 sb = sa;
    for (int k = r0; k < re; k++) {
      const float* rr2 = cur + k*36 + qq*8;
      f32x4 va = *(const f32x4*)rr2;
      f32x4 vb = *(const f32x4*)(rr2 + 4);
      sa.x += va.x; sa.y += va.y; sa.z += va.z; sa.w += va.w;
      sb.x += vb.x; sb.y += vb.y; sb.z += vb.z; sb.w += vb.w;
    }
    float inv = 1.f / (float)(re - r0);
    int b = g >> 15, cell = g & 32767;
    size_t ob = ((size_t)b << 20) + cell;
#pragma unroll
    for (int jj = 0; jj < 4; jj++) {
      outp[ob + ((size_t)(qq*8 + jj)     << 15)] = sa[jj] * inv;
      outp[ob + ((size_t)(qq*8 + jj + 4) << 15)] = sb[jj] * inv;
    }
  }
}

extern "C" void kernel_launch(void* const* d_in, const int* in_sizes, int n_in,
                              void* d_out, int out_size, void* d_ws, size_t ws_size,
                              hipStream_t stream)
{
  const float* p   = (const float*)d_in[0];
  const float* Wp  = (const float*)d_in[1];
  const float* bp  = (const float*)d_in[2];
  const float* f0w = (const float*)d_in[3];
  const float* f0b = (const float*)d_in[4];
  const float* f1w = (const float*)d_in[5];
  const float* f1b = (const float*)d_in[6];
  const float* scw = (const float*)d_in[7];
  const float* wc  = (const float*)d_in[8];
  const float* bc  = (const float*)d_in[9];
  float* outp = (float*)d_out;

  char* wsb = (char*)d_ws;
  int*      gbuf     = (int*)wsb;                         // NPTS
  int*      gsort    = gbuf + NPTS;                       // NPTS
  int*      hist     = gsort + NPTS;                      // BG
  int*      start    = hist + BG;                         // BG+1
  int*      cursor   = start + BG + 1;                    // BG
  int*      texcl    = cursor + BG;                       // BG
  int*      bsum     = texcl + BG;                        // 256
  int*      boff     = bsum + 256;                        // 256
  ushort_t* wpack    = (ushort_t*)(boff + 256);           // 120*512 ushort
  float*    p_sorted = (float*)(wpack + (size_t)120*512); // NPTS*3

  dim3 blk(256);
  dim3 gpts((NPTS + 255)/256);
  dim3 gmega(NPTS/64);          // 6250 blocks
  dim3 gscan(BG/256);           // 256 blocks

  hipMemsetAsync(hist, 0, (size_t)BG*4, stream);
  hipMemsetAsync(outp, 0, (size_t)BG*32*4, stream);
  hipLaunchKernelGGL(k_hist, gpts, blk, 0, stream, p, gbuf, hist);
  hipLaunchKernelGGL(k_scanA, gscan, blk, 0, stream, hist, texcl, bsum);
  hipLaunchKernelGGL(k_scanB, dim3(1), blk, 0, stream, bsum, boff);
  hipLaunchKernelGGL(k_scanC, gscan, blk, 0, stream, texcl, boff, start, cursor);
  hipLaunchKernelGGL(k_scatter, gpts, blk, 0, stream, p, gbuf, cursor, p_sorted, gsort);
  hipLaunchKernelGGL(k_pack, dim3(120), dim3(64), 0, stream, f0w, scw, f1w, wc, Wp, wpack);
  hipLaunchKernelGGL(k_mega, gmega, blk, 0, stream,
                     p_sorted, gsort, start, wpack, bp, f0b, f1b, bc, outp);
}

// Round 6
// 378.574 us; speedup vs baseline: 1.5400x; 1.4732x over previous
//
#include <hip/hip_runtime.h>
#include <math.h>

#define TPTS 200000
#define BB 2
#define NPTS (BB*TPTS)
#define GRID3 32768
#define BG 65536   // BB * GRID3
#define SROWS 176  // staged rows per block (64 pts + cell overhang; max cell ~30)

typedef __attribute__((ext_vector_type(8))) __bf16 bf16x8;
typedef __attribute__((ext_vector_type(4))) float f32x4;
typedef unsigned short ushort_t;

#define MFMA16(a,b,c) __builtin_amdgcn_mfma_f32_16x16x32_bf16(a,b,c,0,0,0)

__device__ __forceinline__ void split8(const float* v, bf16x8& hi, bf16x8& lo)
{
#pragma unroll
  for (int j = 0; j < 8; j++) {
    float f = v[j];
    __bf16 h = (__bf16)f;
    hi[j] = h;
    lo[j] = (__bf16)(f - (float)h);   // exact residual, rounded to bf16
  }
}

// cell id: must match reference fp32 arithmetic exactly
__device__ __forceinline__ int cellof(float p0, float p1, float p2, int t)
{
  const float DEN = (float)(1.0 + 0.1 + 1e-3);
  const float HI  = (float)(1.0 - 1e-3);
  float n0 = fminf(fmaxf(p0/DEN + 0.5f, 0.f), HI);
  float n1 = fminf(fmaxf(p1/DEN + 0.5f, 0.f), HI);
  float n2 = fminf(fmaxf(p2/DEN + 0.5f, 0.f), HI);
  int c0 = (int)floorf(n0*32.f), c1 = (int)floorf(n1*32.f), c2 = (int)floorf(n2*32.f);
  return c0 + 32*(c1 + 32*c2) + (t >= TPTS ? GRID3 : 0);
}

__global__ __launch_bounds__(256) void k_hist(
    const float* __restrict__ p, int* __restrict__ gbuf, int* __restrict__ hist)
{
  int t = blockIdx.x*256 + threadIdx.x;
  if (t >= NPTS) return;
  int g = cellof(p[3*t], p[3*t+1], p[3*t+2], t);
  gbuf[t] = g;
  atomicAdd(hist + g, 1);
}

// 3-kernel parallel exclusive scan of hist[BG]
__global__ __launch_bounds__(256) void k_scanA(
    const int* __restrict__ hist, int* __restrict__ texcl, int* __restrict__ bsum)
{
  __shared__ int sm[256];
  int tid = threadIdx.x;
  int t = blockIdx.x*256 + tid;
  int v = hist[t];
  sm[tid] = v; __syncthreads();
  for (int off = 1; off < 256; off <<= 1) {
    int x = sm[tid];
    int u = (tid >= off) ? sm[tid-off] : 0;
    __syncthreads();
    sm[tid] = x + u;
    __syncthreads();
  }
  texcl[t] = sm[tid] - v;
  if (tid == 255) bsum[blockIdx.x] = sm[255];
}

__global__ __launch_bounds__(256) void k_scanB(
    const int* __restrict__ bsum, int* __restrict__ boff)
{
  __shared__ int sm[256];
  int tid = threadIdx.x;
  int v = bsum[tid];
  sm[tid] = v; __syncthreads();
  for (int off = 1; off < 256; off <<= 1) {
    int x = sm[tid];
    int u = (tid >= off) ? sm[tid-off] : 0;
    __syncthreads();
    sm[tid] = x + u;
    __syncthreads();
  }
  boff[tid] = sm[tid] - v;   // exclusive block offsets
}

__global__ __launch_bounds__(256) void k_scanC(
    const int* __restrict__ texcl, const int* __restrict__ boff,
    int* __restrict__ start, int* __restrict__ cursor)
{
  int t = blockIdx.x*256 + threadIdx.x;
  int v = boff[blockIdx.x] + texcl[t];
  start[t] = v; cursor[t] = v;
  if (t == 0) start[BG] = NPTS;
}

__global__ __launch_bounds__(256) void k_scatter(
    const float* __restrict__ p, const int* __restrict__ gbuf,
    int* __restrict__ cursor, float* __restrict__ p_sorted, int* __restrict__ gsort)
{
  int t = blockIdx.x*256 + threadIdx.x;
  if (t >= NPTS) return;
  int g = gbuf[t];
  int slot = atomicAdd(cursor + g, 1);
  gsort[slot] = g;
  p_sorted[3*slot]   = p[3*t];
  p_sorted[3*slot+1] = p[3*t+1];
  p_sorted[3*slot+2] = p[3*t+2];
}

// pack weights into MFMA B-fragment order (bf16 hi/lo), once.
// frags 0..99: resblock stages; 100..103: wc; 104..119: Wp (60x64, zero-padded K)
__global__ void k_pack(
    const float* __restrict__ f0w, const float* __restrict__ scw,
    const float* __restrict__ f1w, const float* __restrict__ wc,
    const float* __restrict__ Wp,
    ushort_t* __restrict__ wpack)
{
  int f = blockIdx.x, l = threadIdx.x;
  if (f >= 104) {
    int idx = f - 104;
    int c = idx >> 3, t = (idx >> 1) & 3, e = idx & 1;
#pragma unroll
    for (int j = 0; j < 8; j++) {
      int k = c*32 + (l>>4)*8 + j, n = t*16 + (l&15);
      float v = (k < 60) ? Wp[k*64 + n] : 0.f;
      __bf16 h = (__bf16)v;
      __bf16 out = (e == 0) ? h : (__bf16)(v - (float)h);
      union { __bf16 b; ushort_t u; } cv; cv.b = out;
      wpack[((size_t)f*64 + l)*8 + j] = cv.u;
    }
    return;
  }
  const float* W; int c, t, e;
  if (f < 100) {
    int s = f / 20, r = f % 20;
    if (r < 8)       { W = f0w + s*2048; c = r>>2;        t = (r>>1)&1; e = r&1; }
    else if (r < 16) { int q = r-8;  W = scw + s*2048; c = q>>2; t = (q>>1)&1; e = q&1; }
    else             { int q = r-16; W = f1w + s*1024; c = 0;    t = q>>1;     e = q&1; }
  } else { int q = f-100; W = wc; c = 0; t = q>>1; e = q&1; }
#pragma unroll
  for (int j = 0; j < 8; j++) {
    int k = c*32 + (l>>4)*8 + j, n = t*16 + (l&15);
    float v = W[k*32 + n];
    __bf16 h = (__bf16)v;
    __bf16 out = (e == 0) ? h : (__bf16)(v - (float)h);
    union { __bf16 b; ushort_t u; } cv; cv.b = out;
    wpack[((size_t)f*64 + l)*8 + j] = cv.u;
  }
}

// FUSED: per-lane PE entries (A-frag layout) -> MFMA fc_pos -> LDS transpose
// -> MFMA resblock0 -> net AoS [pt][32].
__global__ __launch_bounds__(256) void k_fused0(
    const float* __restrict__ ps,
    const ushort_t* __restrict__ wpPE, const float* __restrict__ bp,
    const ushort_t* __restrict__ wp,
    const float* __restrict__ b0, const float* __restrict__ b1,
    float* __restrict__ net)
{
  __shared__ float xlds[4][16*68];
  __shared__ float hbuf[4][16*36];
  int wave = threadIdx.x >> 6, lane = threadIdx.x & 63;
  int m = lane & 15, q = lane >> 4;
  int pbase = (blockIdx.x*4 + wave)*16;
  int pt = pbase + m;

  // ---- phase 1: positional encoding entries for this lane's A-fragment ----
  float p0 = ps[3*pt], p1 = ps[3*pt+1], p2 = ps[3*pt+2];
  float u0 = 2.f*p0 - 1.f, u1 = 2.f*p1 - 1.f, u2 = 2.f*p2 - 1.f;
  const float PIF = 3.14159265358979323846f;

  float pe[2][8];
#pragma unroll
  for (int c2 = 0; c2 < 2; c2++) {
#pragma unroll
    for (int jj = 0; jj < 8; jj++) {
      int e = c2*32 + q*8 + jj;          // PE row index (runtime via q)
      int l = (e * 43691) >> 18;         // e / 6
      int r = e - l*6;
      bool issin = (r < 3);
      int d = issin ? r : (r - 3);
      float ud = (d == 0) ? u0 : ((d == 1) ? u1 : u2);
      float xval = ldexpf(ud, l);                    // exact *2^l
      float red = xval - 2.f*rintf(0.5f*xval);       // exact mod-2
      float ang = PIF*red + (issin ? 0.f : 1.5707963267948966f);
      float v = __sinf(ang);                         // cos(x)=sin(x+pi/2)
      pe[c2][jj] = (e < 60) ? v : 0.f;               // zero-pad K 60->64
    }
  }
  bf16x8 peh[2], pel[2];
  split8(pe[0], peh[0], pel[0]);
  split8(pe[1], peh[1], pel[1]);

  // x = PE @ Wp + bp  (4 N-tiles)
  f32x4 xacc[4];
#pragma unroll
  for (int t = 0; t < 4; t++) {
    float bb = bp[t*16 + m];
    xacc[t] = (f32x4){bb,bb,bb,bb};
  }
#pragma unroll
  for (int c2 = 0; c2 < 2; c2++)
#pragma unroll
    for (int t = 0; t < 4; t++) {
      bf16x8 bh = *(const bf16x8*)(wpPE + ((size_t)((c2*4+t)*2    )*64 + lane)*8);
      bf16x8 bl = *(const bf16x8*)(wpPE + ((size_t)((c2*4+t)*2 + 1)*64 + lane)*8);
      xacc[t] = MFMA16(peh[c2], bh, xacc[t]);
      xacc[t] = MFMA16(pel[c2], bh, xacc[t]);
      xacc[t] = MFMA16(peh[c2], bl, xacc[t]);
    }

  // D-layout -> A-layout via LDS
  float* xl = xlds[wave];
#pragma unroll
  for (int t = 0; t < 4; t++)
#pragma unroll
    for (int r = 0; r < 4; r++)
      xl[(q*4+r)*68 + t*16 + m] = xacc[t][r];
  __syncthreads();

  float xv[2][8];
#pragma unroll
  for (int c2 = 0; c2 < 2; c2++)
#pragma unroll
    for (int jj = 0; jj < 8; jj++)
      xv[c2][jj] = xl[m*68 + c2*32 + q*8 + jj];

  // ---- phase 2: resblock0 via MFMA ----
  bf16x8 w0f[2][2][2], wsf[2][2][2], w1f[2][2];
#pragma unroll
  for (int c = 0; c < 2; c++)
#pragma unroll
    for (int t = 0; t < 2; t++)
#pragma unroll
      for (int e = 0; e < 2; e++) {
        w0f[c][t][e] = *(const bf16x8*)(wp + ((size_t)(((c*2+t)*2+e)    )*64 + lane)*8);
        wsf[c][t][e] = *(const bf16x8*)(wp + ((size_t)(((c*2+t)*2+e) + 8)*64 + lane)*8);
      }
#pragma unroll
  for (int t = 0; t < 2; t++)
#pragma unroll
    for (int e = 0; e < 2; e++)
      w1f[t][e] = *(const bf16x8*)(wp + ((size_t)(16 + t*2 + e)*64 + lane)*8);

  bf16x8 axh[2], axl[2], arh[2], arl[2];
#pragma unroll
  for (int c = 0; c < 2; c++) {
    float r[8];
#pragma unroll
    for (int j = 0; j < 8; j++) r[j] = fmaxf(xv[c][j], 0.f);
    split8(xv[c], axh[c], axl[c]);
    split8(r,     arh[c], arl[c]);
  }

  f32x4 hacc[2], yacc[2];
#pragma unroll
  for (int t = 0; t < 2; t++) {
    float bb0 = b0[m + 16*t], bb1 = b1[m + 16*t];
    hacc[t] = (f32x4){bb0,bb0,bb0,bb0};
    yacc[t] = (f32x4){bb1,bb1,bb1,bb1};
  }

#pragma unroll
  for (int c = 0; c < 2; c++)
#pragma unroll
    for (int t = 0; t < 2; t++) {
      hacc[t] = MFMA16(arh[c], w0f[c][t][0], hacc[t]);
      hacc[t] = MFMA16(arl[c], w0f[c][t][0], hacc[t]);
      hacc[t] = MFMA16(arh[c], w0f[c][t][1], hacc[t]);
      yacc[t] = MFMA16(axh[c], wsf[c][t][0], yacc[t]);
      yacc[t] = MFMA16(axl[c], wsf[c][t][0], yacc[t]);
      yacc[t] = MFMA16(axh[c], wsf[c][t][1], yacc[t]);
    }

  float* hb = hbuf[wave];
#pragma unroll
  for (int t = 0; t < 2; t++)
#pragma unroll
    for (int r = 0; r < 4; r++)
      hb[(q*4+r)*36 + m + 16*t] = fmaxf(hacc[t][r], 0.f);
  __syncthreads();
  float hv[8];
#pragma unroll
  for (int j = 0; j < 8; j++) hv[j] = hb[m*36 + q*8 + j];
  bf16x8 hh, hl; split8(hv, hh, hl);
#pragma unroll
  for (int t = 0; t < 2; t++) {
    yacc[t] = MFMA16(hh, w1f[t][0], yacc[t]);
    yacc[t] = MFMA16(hl, w1f[t][0], yacc[t]);
    yacc[t] = MFMA16(hh, w1f[t][1], yacc[t]);
  }

#pragma unroll
  for (int t = 0; t < 2; t++)
#pragma unroll
    for (int r = 0; r < 4; r++)
      net[(size_t)(pbase + q*4 + r)*32 + m + 16*t] = yacc[t][r];
}

// FUSED pool+stage: stage netin rows [s,e) in LDS, per-point cell-max loop,
// resblock via MFMA -> netout.  (round-1 verified version)
__global__ __launch_bounds__(256) void k_stage_f(
    const float* __restrict__ netin, float* __restrict__ netout,
    const int* __restrict__ gsort, const int* __restrict__ start,
    const ushort_t* __restrict__ wp,
    const float* __restrict__ b0, const float* __restrict__ b1)
{
  __shared__ float sbuf[SROWS*36];   // staging (stride 36); reused as h-transpose
  int tid = threadIdx.x;
  int P0 = blockIdx.x*64;
  int s = start[gsort[P0]];
  int e = start[gsort[P0+63] + 1];
  int n = e - s; if (n > SROWS) n = SROWS;

  for (int idx = tid; idx < n*8; idx += 256) {
    int r = idx >> 3, c = idx & 7;
    *(f32x4*)(sbuf + r*36 + c*4) =
      *(const f32x4*)(netin + ((size_t)(s + r))*32 + c*4);
  }
  __syncthreads();

  int wave = tid >> 6, lane = tid & 63;
  int m = lane & 15, q = lane >> 4;
  int pbase = P0 + wave*16;
  int pt = pbase + m;
  int g = gsort[pt];
  int cs = start[g] - s, ce = start[g+1] - s;

  float xv[2][8];
  {
    const float* xr = sbuf + (pt - s)*36 + q*8;
    *(f32x4*)&xv[0][0] = *(const f32x4*)xr;
    *(f32x4*)&xv[0][4] = *(const f32x4*)(xr + 4);
  }
  {
    f32x4 ma = (f32x4){-INFINITY,-INFINITY,-INFINITY,-INFINITY};
    f32x4 mb = ma;
    for (int k = cs; k < ce; k++) {
      const float* rr = sbuf + k*36 + q*8;
      f32x4 va = *(const f32x4*)rr;
      f32x4 vb = *(const f32x4*)(rr + 4);
      ma.x = fmaxf(ma.x, va.x); ma.y = fmaxf(ma.y, va.y);
      ma.z = fmaxf(ma.z, va.z); ma.w = fmaxf(ma.w, va.w);
      mb.x = fmaxf(mb.x, vb.x); mb.y = fmaxf(mb.y, vb.y);
      mb.z = fmaxf(mb.z, vb.z); mb.w = fmaxf(mb.w, vb.w);
    }
    *(f32x4*)&xv[1][0] = ma;
    *(f32x4*)&xv[1][4] = mb;
  }

  bf16x8 w0f[2][2][2], wsf[2][2][2], w1f[2][2];
#pragma unroll
  for (int c = 0; c < 2; c++)
#pragma unroll
    for (int t = 0; t < 2; t++)
#pragma unroll
      for (int e2 = 0; e2 < 2; e2++) {
        w0f[c][t][e2] = *(const bf16x8*)(wp + ((size_t)(((c*2+t)*2+e2)    )*64 + lane)*8);
        wsf[c][t][e2] = *(const bf16x8*)(wp + ((size_t)(((c*2+t)*2+e2) + 8)*64 + lane)*8);
      }
#pragma unroll
  for (int t = 0; t < 2; t++)
#pragma unroll
    for (int e2 = 0; e2 < 2; e2++)
      w1f[t][e2] = *(const bf16x8*)(wp + ((size_t)(16 + t*2 + e2)*64 + lane)*8);

  bf16x8 axh[2], axl[2], arh[2], arl[2];
#pragma unroll
  for (int c = 0; c < 2; c++) {
    float r[8];
#pragma unroll
    for (int j = 0; j < 8; j++) r[j] = fmaxf(xv[c][j], 0.f);
    split8(xv[c], axh[c], axl[c]);
    split8(r,     arh[c], arl[c]);
  }

  f32x4 hacc[2], yacc[2];
#pragma unroll
  for (int t = 0; t < 2; t++) {
    float bb0 = b0[m + 16*t], bb1 = b1[m + 16*t];
    hacc[t] = (f32x4){bb0,bb0,bb0,bb0};
    yacc[t] = (f32x4){bb1,bb1,bb1,bb1};
  }

#pragma unroll
  for (int c = 0; c < 2; c++)
#pragma unroll
    for (int t = 0; t < 2; t++) {
      hacc[t] = MFMA16(arh[c], w0f[c][t][0], hacc[t]);
      hacc[t] = MFMA16(arl[c], w0f[c][t][0], hacc[t]);
      hacc[t] = MFMA16(arh[c], w0f[c][t][1], hacc[t]);
      yacc[t] = MFMA16(axh[c], wsf[c][t][0], yacc[t]);
      yacc[t] = MFMA16(axl[c], wsf[c][t][0], yacc[t]);
      yacc[t] = MFMA16(axh[c], wsf[c][t][1], yacc[t]);
    }

  __syncthreads();   // all staging reads done -> safe to reuse sbuf
  float* hb = sbuf + wave*576;
#pragma unroll
  for (int t = 0; t < 2; t++)
#pragma unroll
    for (int r = 0; r < 4; r++)
      hb[(q*4+r)*36 + m + 16*t] = fmaxf(hacc[t][r], 0.f);
  __syncthreads();
  float hv[8];
#pragma unroll
  for (int j = 0; j < 8; j++) hv[j] = hb[m*36 + q*8 + j];
  bf16x8 hh, hl; split8(hv, hh, hl);
#pragma unroll
  for (int t = 0; t < 2; t++) {
    yacc[t] = MFMA16(hh, w1f[t][0], yacc[t]);
    yacc[t] = MFMA16(hl, w1f[t][0], yacc[t]);
    yacc[t] = MFMA16(hh, w1f[t][1], yacc[t]);
  }

#pragma unroll
  for (int t = 0; t < 2; t++)
#pragma unroll
    for (int r = 0; r < 4; r++)
      netout[(size_t)(pbase + q*4 + r)*32 + m + 16*t] = yacc[t][r];
}

// FINAL: pool + resblock4 for ALL staged rows (y in regs) + fc_c + per-cell
// mean, grid written directly. No per-point c output, no k_mean.
__global__ __launch_bounds__(256) void k_final_f(
    const float* __restrict__ netin,
    const int* __restrict__ gsort, const int* __restrict__ start,
    const ushort_t* __restrict__ wp, const ushort_t* __restrict__ wpc,
    const float* __restrict__ b0, const float* __restrict__ b1,
    const float* __restrict__ bc,
    float* __restrict__ outp)
{
  __shared__ float sbuf[SROWS*36];   // staging; later overwritten with c rows
  __shared__ float hbuf[4*576];      // wave-private h / y transpose scratch
  int tid = threadIdx.x;
  int P0 = blockIdx.x*64;
  int s = start[gsort[P0]];
  int e = start[gsort[P0+63] + 1];
  int n = e - s; if (n > SROWS) n = SROWS;
  int T = (n + 15) >> 4;

  for (int idx = tid; idx < n*8; idx += 256) {
    int r = idx >> 3, c = idx & 7;
    *(f32x4*)(sbuf + r*36 + c*4) =
      *(const f32x4*)(netin + ((size_t)(s + r))*32 + c*4);
  }
  __syncthreads();

  int wave = tid >> 6, lane = tid & 63;
  int m = lane & 15, q = lane >> 4;
  float* hb = hbuf + wave*576;

  bf16x8 w0f[2][2][2], wsf[2][2][2], w1f[2][2], wcf[2][2];
#pragma unroll
  for (int c = 0; c < 2; c++)
#pragma unroll
    for (int t = 0; t < 2; t++)
#pragma unroll
      for (int e2 = 0; e2 < 2; e2++) {
        w0f[c][t][e2] = *(const bf16x8*)(wp + ((size_t)(((c*2+t)*2+e2)    )*64 + lane)*8);
        wsf[c][t][e2] = *(const bf16x8*)(wp + ((size_t)(((c*2+t)*2+e2) + 8)*64 + lane)*8);
      }
#pragma unroll
  for (int t = 0; t < 2; t++)
#pragma unroll
    for (int e2 = 0; e2 < 2; e2++) {
      w1f[t][e2] = *(const bf16x8*)(wp  + ((size_t)(16 + t*2 + e2)*64 + lane)*8);
      wcf[t][e2] = *(const bf16x8*)(wpc + ((size_t)(     t*2 + e2)*64 + lane)*8);
    }

  // ---- pass 1: resblock4 for all staged rows; y kept in registers ----
#define FTILE(TT, Y0out, Y1out) do {                                          \
    int rbase = (TT)*16;                                                      \
    int rr0 = rbase + m;                                                      \
    int rsX = (rr0 < n) ? rr0 : (n - 1);                                      \
    float xv[2][8];                                                           \
    { const float* xr = sbuf + rsX*36 + q*8;                                  \
      *(f32x4*)&xv[0][0] = *(const f32x4*)xr;                                 \
      *(f32x4*)&xv[0][4] = *(const f32x4*)(xr + 4); }                         \
    { int gX = gsort[s + rsX];                                                \
      int csX = start[gX] - s, ceX = start[gX+1] - s; if (ceX > n) ceX = n;   \
      f32x4 ma = (f32x4){-INFINITY,-INFINITY,-INFINITY,-INFINITY};            \
      f32x4 mb = ma;                                                          \
      for (int k = csX; k < ceX; k++) {                                       \
        const float* rr2 = sbuf + k*36 + q*8;                                 \
        f32x4 va = *(const f32x4*)rr2;                                        \
        f32x4 vb = *(const f32x4*)(rr2 + 4);                                  \
        ma.x = fmaxf(ma.x, va.x); ma.y = fmaxf(ma.y, va.y);                   \
        ma.z = fmaxf(ma.z, va.z); ma.w = fmaxf(ma.w, va.w);                   \
        mb.x = fmaxf(mb.x, vb.x); mb.y = fmaxf(mb.y, vb.y);                   \
        mb.z = fmaxf(mb.z, vb.z); mb.w = fmaxf(mb.w, vb.w);                   \
      }                                                                       \
      *(f32x4*)&xv[1][0] = ma;                                                \
      *(f32x4*)&xv[1][4] = mb; }                                              \
    bf16x8 axh[2], axl[2], arh[2], arl[2];                                    \
    _Pragma("unroll")                                                         \
    for (int c = 0; c < 2; c++) {                                             \
      float rv[8];                                                            \
      _Pragma("unroll")                                                       \
      for (int j = 0; j < 8; j++) rv[j] = fmaxf(xv[c][j], 0.f);               \
      split8(xv[c], axh[c], axl[c]);                                          \
      split8(rv,    arh[c], arl[c]);                                          \
    }                                                                         \
    f32x4 hacc[2], yacc[2];                                                   \
    _Pragma("unroll")                                                         \
    for (int t2 = 0; t2 < 2; t2++) {                                          \
      float bb0 = b0[m + 16*t2], bb1 = b1[m + 16*t2];                         \
      hacc[t2] = (f32x4){bb0,bb0,bb0,bb0};                                    \
      yacc[t2] = (f32x4){bb1,bb1,bb1,bb1};                                    \
    }                                                                         \
    _Pragma("unroll")                                                         \
    for (int c = 0; c < 2; c++)                                               \
      _Pragma("unroll")                                                       \
      for (int t2 = 0; t2 < 2; t2++) {                                        \
        hacc[t2] = MFMA16(arh[c], w0f[c][t2][0], hacc[t2]);                   \
        hacc[t2] = MFMA16(arl[c], w0f[c][t2][0], hacc[t2]);                   \
        hacc[t2] = MFMA16(arh[c], w0f[c][t2][1], hacc[t2]);                   \
        yacc[t2] = MFMA16(axh[c], wsf[c][t2][0], yacc[t2]);                   \
        yacc[t2] = MFMA16(axl[c], wsf[c][t2][0], yacc[t2]);                   \
        yacc[t2] = MFMA16(axh[c], wsf[c][t2][1], yacc[t2]);                   \
      }                                                                       \
    _Pragma("unroll")                                                         \
    for (int t2 = 0; t2 < 2; t2++)                                            \
      _Pragma("unroll")                                                       \
      for (int r2 = 0; r2 < 4; r2++)                                          \
        hb[(q*4+r2)*36 + m + 16*t2] = fmaxf(hacc[t2][r2], 0.f);               \
    __threadfence_block();                                                    \
    { float hv[8];                                                            \
      _Pragma("unroll")                                                       \
      for (int j = 0; j < 8; j++) hv[j] = hb[m*36 + q*8 + j];                 \
      bf16x8 hh, hl; split8(hv, hh, hl);                                      \
      _Pragma("unroll")                                                       \
      for (int t2 = 0; t2 < 2; t2++) {                                        \
        yacc[t2] = MFMA16(hh, w1f[t2][0], yacc[t2]);                          \
        yacc[t2] = MFMA16(hl, w1f[t2][0], yacc[t2]);                          \
        yacc[t2] = MFMA16(hh, w1f[t2][1], yacc[t2]);                          \
      } }                                                                     \
    __threadfence_block();                                                    \
    Y0out = yacc[0]; Y1out = yacc[1];                                         \
  } while (0)

  f32x4 yA0, yA1, yB0, yB1, yC0, yC1;
  {
    int t0 = wave, t1 = wave + 4, t2 = wave + 8;
    if (t0 < T) FTILE(t0, yA0, yA1);
    if (t1 < T) FTILE(t1, yB0, yB1);
    if (t2 < T) FTILE(t2, yC0, yC1);
  }
  __syncthreads();   // all pooling reads of sbuf done -> safe to overwrite

  // ---- pass 2+3: y -> sbuf rows, transpose-read, fc_c, c -> sbuf rows ----
#define CTILE(TT, Y0in, Y1in) do {                                            \
    int rbase = (TT)*16;                                                      \
    _Pragma("unroll")                                                         \
    for (int r2 = 0; r2 < 4; r2++) {                                          \
      sbuf[(rbase + q*4 + r2)*36 + m]      = Y0in[r2];                        \
      sbuf[(rbase + q*4 + r2)*36 + m + 16] = Y1in[r2];                        \
    }                                                                         \
    __threadfence_block();                                                    \
    float yv[8];                                                              \
    { const float* yr = sbuf + (rbase + m)*36 + q*8;                          \
      *(f32x4*)&yv[0] = *(const f32x4*)yr;                                    \
      *(f32x4*)&yv[4] = *(const f32x4*)(yr + 4); }                            \
    bf16x8 yh, yl; split8(yv, yh, yl);                                        \
    float bb0 = bc[m], bb1 = bc[16+m];                                        \
    f32x4 c0 = (f32x4){bb0,bb0,bb0,bb0};                                      \
    f32x4 c1 = (f32x4){bb1,bb1,bb1,bb1};                                      \
    c0 = MFMA16(yh, wcf[0][0], c0); c0 = MFMA16(yl, wcf[0][0], c0);           \
    c0 = MFMA16(yh, wcf[0][1], c0);                                           \
    c1 = MFMA16(yh, wcf[1][0], c1); c1 = MFMA16(yl, wcf[1][0], c1);           \
    c1 = MFMA16(yh, wcf[1][1], c1);                                           \
    __threadfence_block();                                                    \
    _Pragma("unroll")                                                         \
    for (int r2 = 0; r2 < 4; r2++) {                                          \
      sbuf[(rbase + q*4 + r2)*36 + m]      = c0[r2];                          \
      sbuf[(rbase + q*4 + r2)*36 + m + 16] = c1[r2];                          \
    }                                                                         \
  } while (0)

  {
    int t0 = wave, t1 = wave + 4, t2 = wave + 8;
    if (t0 < T) CTILE(t0, yA0, yA1);
    if (t1 < T) CTILE(t1, yB0, yB1);
    if (t2 < T) CTILE(t2, yC0, yC1);
  }
  __syncthreads();

  // ---- pass 4: per-cell mean for owned cells (start row in our 64 pts) ----
  {
    int o = tid >> 2, qq = tid & 3;
    int r = (P0 - s) + o;
    int g2 = gsort[P0 + o];
    int cs2 = start[g2] - s;
    if (cs2 == r) {   // this point starts its cell -> we own it
      int ce2 = start[g2+1] - s; if (ce2 > n) ce2 = n;
      f32x4 sa = (f32x4){0.f,0.f,0.f,0.f};
      f32x4 sb = sa;
      for (int k = cs2; k < ce2; k++) {
        const float* rr2 = sbuf + k*36 + qq*8;
        f32x4 va = *(const f32x4*)rr2;
        f32x4 vb = *(const f32x4*)(rr2 + 4);
        sa.x += va.x; sa.y += va.y; sa.z += va.z; sa.w += va.w;
        sb.x += vb.x; sb.y += vb.y; sb.z += vb.z; sb.w += vb.w;
      }
      float inv = 1.f / (float)(ce2 - cs2);
      int b2 = g2 >> 15, cell = g2 & 32767;
      size_t ob = ((size_t)b2 << 20) + cell;
#pragma unroll
      for (int jj = 0; jj < 4; jj++) {
        outp[ob + ((size_t)(qq*8 + jj)     << 15)] = sa[jj] * inv;
        outp[ob + ((size_t)(qq*8 + jj + 4) << 15)] = sb[jj] * inv;
      }
    }
  }
}

extern "C" void kernel_launch(void* const* d_in, const int* in_sizes, int n_in,
                              void* d_out, int out_size, void* d_ws, size_t ws_size,
                              hipStream_t stream)
{
  const float* p   = (const float*)d_in[0];
  const float* Wp  = (const float*)d_in[1];
  const float* bp  = (const float*)d_in[2];
  const float* f0w = (const float*)d_in[3];
  const float* f0b = (const float*)d_in[4];
  const float* f1w = (const float*)d_in[5];
  const float* f1b = (const float*)d_in[6];
  const float* scw = (const float*)d_in[7];
  const float* wc  = (const float*)d_in[8];
  const float* bc  = (const float*)d_in[9];
  float* outp = (float*)d_out;

  char* wsb = (char*)d_ws;
  float*    netA     = (float*)wsb;                       // NPTS*32 f32 = 51.2 MB
  float*    netB     = netA + (size_t)NPTS*32;            // NPTS*32 f32 = 51.2 MB
  int*      gbuf     = (int*)(netB + (size_t)NPTS*32);    // NPTS
  int*      gsort    = gbuf + NPTS;                       // NPTS
  int*      hist     = gsort + NPTS;                      // BG
  int*      start    = hist + BG;                         // BG+1
  int*      cursor   = start + BG + 1;                    // BG
  int*      texcl    = cursor + BG;                       // BG
  int*      bsum     = texcl + BG;                        // 256
  int*      boff     = bsum + 256;                        // 256
  ushort_t* wpack    = (ushort_t*)(boff + 256);           // 120*512 ushort
  float*    p_sorted = (float*)(wpack + (size_t)120*512); // NPTS*3

  dim3 blk(256);
  dim3 gpts((NPTS + 255)/256);
  dim3 gmfma(NPTS/64);          // 6250 blocks
  dim3 gscan(BG/256);           // 256 blocks

  hipMemsetAsync(hist, 0, (size_t)BG*4, stream);
  hipMemsetAsync(outp, 0, (size_t)BG*32*4, stream);
  hipLaunchKernelGGL(k_hist, gpts, blk, 0, stream, p, gbuf, hist);
  hipLaunchKernelGGL(k_scanA, gscan, blk, 0, stream, hist, texcl, bsum);
  hipLaunchKernelGGL(k_scanB, dim3(1), blk, 0, stream, bsum, boff);
  hipLaunchKernelGGL(k_scanC, gscan, blk, 0, stream, texcl, boff, start, cursor);
  hipLaunchKernelGGL(k_scatter, gpts, blk, 0, stream, p, gbuf, cursor, p_sorted, gsort);
  hipLaunchKernelGGL(k_pack, dim3(120), dim3(64), 0, stream, f0w, scw, f1w, wc, Wp, wpack);
  hipLaunchKernelGGL(k_fused0, gmfma, blk, 0, stream,
                     p_sorted, wpack + (size_t)104*512, bp,
                     wpack + (size_t)0*20*512, f0b + 0*32, f1b + 0*32, netA);
  hipLaunchKernelGGL(k_stage_f, gmfma, blk, 0, stream, netA, netB, gsort, start,
                     wpack + (size_t)1*20*512, f0b + 1*32, f1b + 1*32);
  hipLaunchKernelGGL(k_stage_f, gmfma, blk, 0, stream, netB, netA, gsort, start,
                     wpack + (size_t)2*20*512, f0b + 2*32, f1b + 2*32);
  hipLaunchKernelGGL(k_stage_f, gmfma, blk, 0, stream, netA, netB, gsort, start,
                     wpack + (size_t)3*20*512, f0b + 3*32, f1b + 3*32);
  hipLaunchKernelGGL(k_final_f, gmfma, blk, 0, stream, netB, gsort, start,
                     wpack + (size_t)4*20*512, wpack + (size_t)100*512,
                     f0b + 4*32, f1b + 4*32, bc, outp);
}